// Round 1
// baseline (243.280 us; speedup 1.0000x reference)
//
#include <hip/hip_runtime.h>
#include <hip/hip_bf16.h>

// RoPE fused with per-row max/min observation.
// x: (H=32, T=8192, D=128) fp32; cos/sin: (T, D) fp32.
// out[h,t,j] = x[h,t,j]*cos[t,j] + rot(x)[h,t,j]*sin[t,j]
//   rot: first half = -x2, second half = +x1 (halves of size 64).
// obs_max/obs_min: (H,T) row-wise max/min of out.
// scale_x / scale_cos / scale_sin are unused by the reference.

#define HH 32
#define TT 8192
#define DD 128

__global__ __launch_bounds__(256) void rope_obs_kernel(
    const float* __restrict__ x,
    const float* __restrict__ cosp,
    const float* __restrict__ sinp,
    float* __restrict__ out,
    float* __restrict__ obs_max,
    float* __restrict__ obs_min)
{
    // One 32-lane half-wave per row (h,t). Each lane owns one float4 (16B).
    int tid    = blockIdx.x * blockDim.x + threadIdx.x;
    int lane32 = tid & 31;        // float4 index within the row [0,32)
    long long row = tid >> 5;     // global row index in [0, H*T)
    int t = (int)(row & (TT - 1));

    const float4* x4 = (const float4*)x    + row * 32 + lane32;
    const float4* c4 = (const float4*)cosp + (long long)t * 32 + lane32;
    const float4* s4 = (const float4*)sinp + (long long)t * 32 + lane32;

    float4 xv = *x4;
    float4 cv = *c4;
    float4 sv = *s4;

    // Partner float4 lives at float4-index l^16 within the row.
    // xor-16 stays inside each 32-lane half of the wave64.
    float4 pv;
    pv.x = __shfl_xor(xv.x, 16);
    pv.y = __shfl_xor(xv.y, 16);
    pv.z = __shfl_xor(xv.z, 16);
    pv.w = __shfl_xor(xv.w, 16);

    // first half of row (lane32 < 16): rotated = -x2 ; second half: +x1
    float sgn = (lane32 < 16) ? -1.0f : 1.0f;

    float4 ov;
    ov.x = fmaf(xv.x, cv.x, sgn * pv.x * sv.x);
    ov.y = fmaf(xv.y, cv.y, sgn * pv.y * sv.y);
    ov.z = fmaf(xv.z, cv.z, sgn * pv.z * sv.z);
    ov.w = fmaf(xv.w, cv.w, sgn * pv.w * sv.w);

    float4* o4 = (float4*)out + row * 32 + lane32;
    *o4 = ov;

    // Row-wise max/min: 4 components then 5-step butterfly across 32 lanes.
    float mx = fmaxf(fmaxf(ov.x, ov.y), fmaxf(ov.z, ov.w));
    float mn = fminf(fminf(ov.x, ov.y), fminf(ov.z, ov.w));
    #pragma unroll
    for (int m = 16; m >= 1; m >>= 1) {
        mx = fmaxf(mx, __shfl_xor(mx, m));
        mn = fminf(mn, __shfl_xor(mn, m));
    }
    if (lane32 == 0) {
        obs_max[row] = mx;
        obs_min[row] = mn;
    }
}

extern "C" void kernel_launch(void* const* d_in, const int* in_sizes, int n_in,
                              void* d_out, int out_size, void* d_ws, size_t ws_size,
                              hipStream_t stream) {
    const float* x    = (const float*)d_in[0];
    // d_in[1] = scale_x   (unused)
    const float* cosp = (const float*)d_in[2];
    // d_in[3] = scale_cos (unused)
    const float* sinp = (const float*)d_in[4];
    // d_in[5] = scale_sin (unused)

    float* out      = (float*)d_out;
    float* obs_max  = out + (long long)HH * TT * DD;       // 33,554,432
    float* obs_min  = obs_max + (long long)HH * TT;        // +262,144

    const int total_threads = HH * TT * 32;                // 32 lanes per row
    const int block = 256;
    const int grid  = total_threads / block;               // 32768

    rope_obs_kernel<<<grid, block, 0, stream>>>(x, cosp, sinp, out, obs_max, obs_min);
}

// Round 3
// 240.033 us; speedup vs baseline: 1.0135x; 1.0135x over previous
//
#include <hip/hip_runtime.h>
#include <hip/hip_bf16.h>

// RoPE fused with per-row max/min observation.
// x: (H=32, T=8192, D=128) fp32; cos/sin: (T, D) fp32.
// out[..., :64] = x1*c1 - x2*s1 ; out[..., 64:] = x2*c2 + x1*s2
// obs_max/obs_min: (H,T) row-wise max/min of out.
// scale_x / scale_cos / scale_sin are unused by the reference.
//
// Layout: 16 lanes per row; lane l owns float4 pair (elems 4l..4l+3 and
// 64+4l..64+4l+3). No cross-lane shuffles needed for the rotate pairing.
// Nontemporal loads/stores (via native clang vector type — HIP's float4
// class is rejected by the builtin) for streamed x/out keep L2 free for
// the 32x-reused cos/sin tables.

#define HH 32
#define TT 8192
#define DD 128

typedef float vf4 __attribute__((ext_vector_type(4)));

__global__ __launch_bounds__(256) void rope_obs_kernel(
    const float* __restrict__ x,
    const float* __restrict__ cosp,
    const float* __restrict__ sinp,
    float* __restrict__ out,
    float* __restrict__ obs_max,
    float* __restrict__ obs_min)
{
    int tid  = blockIdx.x * blockDim.x + threadIdx.x;
    int lane = tid & 15;          // float4 index within first half of row [0,16)
    long long row = tid >> 4;     // global row index in [0, H*T)
    int t = (int)(row & (TT - 1));

    const vf4* xr = (const vf4*)x    + row * 32;
    const vf4* cr = (const vf4*)cosp + (long long)t * 32;
    const vf4* sr = (const vf4*)sinp + (long long)t * 32;

    // Two independent 16B loads per stream — no shuffle dependency chain.
    vf4 x1 = __builtin_nontemporal_load(xr + lane);
    vf4 x2 = __builtin_nontemporal_load(xr + 16 + lane);
    vf4 c1 = cr[lane];
    vf4 c2 = cr[16 + lane];
    vf4 s1 = sr[lane];
    vf4 s2 = sr[16 + lane];

    vf4 o1, o2;
    o1.x = fmaf(x1.x, c1.x, -x2.x * s1.x);
    o1.y = fmaf(x1.y, c1.y, -x2.y * s1.y);
    o1.z = fmaf(x1.z, c1.z, -x2.z * s1.z);
    o1.w = fmaf(x1.w, c1.w, -x2.w * s1.w);
    o2.x = fmaf(x2.x, c2.x,  x1.x * s2.x);
    o2.y = fmaf(x2.y, c2.y,  x1.y * s2.y);
    o2.z = fmaf(x2.z, c2.z,  x1.z * s2.z);
    o2.w = fmaf(x2.w, c2.w,  x1.w * s2.w);

    vf4* orow = (vf4*)out + row * 32;
    __builtin_nontemporal_store(o1, orow + lane);
    __builtin_nontemporal_store(o2, orow + 16 + lane);

    // Row max/min: 8 local elems, then 4-step butterfly across the 16 lanes.
    float mx = fmaxf(fmaxf(fmaxf(o1.x, o1.y), fmaxf(o1.z, o1.w)),
                     fmaxf(fmaxf(o2.x, o2.y), fmaxf(o2.z, o2.w)));
    float mn = fminf(fminf(fminf(o1.x, o1.y), fminf(o1.z, o1.w)),
                     fminf(fminf(o2.x, o2.y), fminf(o2.z, o2.w)));
    #pragma unroll
    for (int m = 8; m >= 1; m >>= 1) {
        mx = fmaxf(mx, __shfl_xor(mx, m));
        mn = fminf(mn, __shfl_xor(mn, m));
    }
    if (lane == 0) {
        obs_max[row] = mx;
        obs_min[row] = mn;
    }
}

extern "C" void kernel_launch(void* const* d_in, const int* in_sizes, int n_in,
                              void* d_out, int out_size, void* d_ws, size_t ws_size,
                              hipStream_t stream) {
    const float* x    = (const float*)d_in[0];
    // d_in[1] = scale_x   (unused)
    const float* cosp = (const float*)d_in[2];
    // d_in[3] = scale_cos (unused)
    const float* sinp = (const float*)d_in[4];
    // d_in[5] = scale_sin (unused)

    float* out      = (float*)d_out;
    float* obs_max  = out + (long long)HH * TT * DD;       // 33,554,432
    float* obs_min  = obs_max + (long long)HH * TT;        // +262,144

    const int total_threads = HH * TT * 16;                // 16 lanes per row
    const int block = 256;
    const int grid  = total_threads / block;               // 16384

    rope_obs_kernel<<<grid, block, 0, stream>>>(x, cosp, sinp, out, obs_max, obs_min);
}

// Round 4
// 238.002 us; speedup vs baseline: 1.0222x; 1.0085x over previous
//
#include <hip/hip_runtime.h>
#include <hip/hip_bf16.h>

// RoPE fused with per-row max/min observation.
// x: (H=32, T=8192, D=128) fp32; cos/sin: (T, D) fp32.
// out[..., :64] = x1*c1 - x2*s1 ; out[..., 64:] = x2*c2 + x1*s2
// obs_max/obs_min: (H,T) row-wise max/min of out.
// scale_x / scale_cos / scale_sin are unused by the reference.
//
// R3 theory: VMEM-instruction-issue bound (1 VMEM instr/cyc/CU). Batch 4
// heads per thread: cos/sin (t-dependent only) loaded once, reused 4x.
// VMEM instrs per 4 rows: 32 -> 20, pushing issue time (~34 us) below the
// HBM streaming floor (~44 us for 278 MB compulsory traffic).
//
// Mapping: 16 lanes per (t, head-group) unit; lane l owns float4 pair
// (elems 4l and 64+4l) of each of the 4 heads' rows. idx = tid>>4;
// t = idx & 8191 (fast-varying -> wave covers 4 consecutive t: x loads are
// 4x512B-contiguous per instruction per head); hg = idx>>13 picks heads
// 4hg..4hg+3. Nontemporal on streamed x/out; cached loads for c/s.

#define HH 32
#define TT 8192
#define DD 128

typedef float vf4 __attribute__((ext_vector_type(4)));

__global__ __launch_bounds__(256) void rope_obs_kernel(
    const float* __restrict__ x,
    const float* __restrict__ cosp,
    const float* __restrict__ sinp,
    float* __restrict__ out,
    float* __restrict__ obs_max,
    float* __restrict__ obs_min)
{
    int tid  = blockIdx.x * blockDim.x + threadIdx.x;
    int lane = tid & 15;            // float4 index within first half of row
    int idx  = tid >> 4;            // [0, T * H/4)
    int t    = idx & (TT - 1);      // fast-varying for contiguity
    int hg   = idx >> 13;           // head group [0, 8)
    int h0   = hg << 2;             // first head of group

    const vf4* cr = (const vf4*)cosp + (size_t)t * 32;
    const vf4* sr = (const vf4*)sinp + (size_t)t * 32;
    vf4 c1 = cr[lane];
    vf4 c2 = cr[16 + lane];
    vf4 s1 = sr[lane];
    vf4 s2 = sr[16 + lane];

    const size_t hstride = (size_t)TT * 32;                 // vf4 per head
    size_t rowbase = ((size_t)h0 * TT + t) * 32;            // vf4 units
    const vf4* x4 = (const vf4*)x;
    vf4* o4 = (vf4*)out;

    // Issue all 8 x-loads up front for MLP.
    vf4 xs1[4], xs2[4];
    #pragma unroll
    for (int i = 0; i < 4; ++i) {
        const vf4* xr = x4 + rowbase + (size_t)i * hstride;
        xs1[i] = __builtin_nontemporal_load(xr + lane);
        xs2[i] = __builtin_nontemporal_load(xr + 16 + lane);
    }

    #pragma unroll
    for (int i = 0; i < 4; ++i) {
        vf4 x1 = xs1[i], x2 = xs2[i];
        vf4 o1, o2;
        o1.x = fmaf(x1.x, c1.x, -x2.x * s1.x);
        o1.y = fmaf(x1.y, c1.y, -x2.y * s1.y);
        o1.z = fmaf(x1.z, c1.z, -x2.z * s1.z);
        o1.w = fmaf(x1.w, c1.w, -x2.w * s1.w);
        o2.x = fmaf(x2.x, c2.x,  x1.x * s2.x);
        o2.y = fmaf(x2.y, c2.y,  x1.y * s2.y);
        o2.z = fmaf(x2.z, c2.z,  x1.z * s2.z);
        o2.w = fmaf(x2.w, c2.w,  x1.w * s2.w);

        vf4* orow = o4 + rowbase + (size_t)i * hstride;
        __builtin_nontemporal_store(o1, orow + lane);
        __builtin_nontemporal_store(o2, orow + 16 + lane);

        // Row max/min: 8 local elems, then 4-step butterfly over 16 lanes.
        float mx = fmaxf(fmaxf(fmaxf(o1.x, o1.y), fmaxf(o1.z, o1.w)),
                         fmaxf(fmaxf(o2.x, o2.y), fmaxf(o2.z, o2.w)));
        float mn = fminf(fminf(fminf(o1.x, o1.y), fminf(o1.z, o1.w)),
                         fminf(fminf(o2.x, o2.y), fminf(o2.z, o2.w)));
        #pragma unroll
        for (int m = 8; m >= 1; m >>= 1) {
            mx = fmaxf(mx, __shfl_xor(mx, m));
            mn = fminf(mn, __shfl_xor(mn, m));
        }
        if (lane == 0) {
            size_t orow_idx = (size_t)(h0 + i) * TT + t;
            obs_max[orow_idx] = mx;
            obs_min[orow_idx] = mn;
        }
    }
}

extern "C" void kernel_launch(void* const* d_in, const int* in_sizes, int n_in,
                              void* d_out, int out_size, void* d_ws, size_t ws_size,
                              hipStream_t stream) {
    const float* x    = (const float*)d_in[0];
    // d_in[1] = scale_x   (unused)
    const float* cosp = (const float*)d_in[2];
    // d_in[3] = scale_cos (unused)
    const float* sinp = (const float*)d_in[4];
    // d_in[5] = scale_sin (unused)

    float* out      = (float*)d_out;
    float* obs_max  = out + (size_t)HH * TT * DD;          // 33,554,432
    float* obs_min  = obs_max + (size_t)HH * TT;           // +262,144

    const int total_threads = TT * 16 * (HH / 4);          // 1,048,576
    const int block = 256;
    const int grid  = total_threads / block;               // 4096

    rope_obs_kernel<<<grid, block, 0, stream>>>(x, cosp, sinp, out, obs_max, obs_min);
}